// Round 15
// baseline (195.109 us; speedup 1.0000x reference)
//
#include <hip/hip_runtime.h>
#include <hip/hip_bf16.h>

// RelativeSemanticLoss via bf16 MFMA GEMM + fused softmax-NLL epilogue.
// R15 = R14/R11 base (16x16x32 MFMA, async global_load_lds dbuf, 3 blk/CU,
// pred LDS XOR-swizzle) + ONE change: rsl_final folded into the last-arriving
// mfma block (device-scope atomics + threadfence). No idx prefetch (R13's
// spill culprit). Saves one graph-serialized launch.

#define NUM_CLS 150
#define NT_TILES 10      // 160 padded classes
#define D_DIM   512
#define HW_DIM  65536
#define IGNORE_L 255

typedef __attribute__((ext_vector_type(8))) short bf16x8;
typedef __attribute__((ext_vector_type(4))) float f32x4;
typedef __attribute__((ext_vector_type(4))) unsigned int u32x4;

#define GLOAD16(gsrc, ldst) \
    __builtin_amdgcn_global_load_lds((const __attribute__((address_space(1))) void*)(gsrc), \
                                     (__attribute__((address_space(3))) void*)(ldst), 16, 0, 0)

static __device__ __forceinline__ short f2bf(float f) {
    __hip_bfloat16 h = __float2bfloat16(f);   // RNE
    return __builtin_bit_cast(short, h);
}

// Pack cls (150x512 fp32) -> bf16 fragments in lane-linear order:
// packed[(s*10+nt)*512 + l*8 + j] (ushort) = bf16(cls[nt*16+(l&15)][s*32+(l>>4)*8+j])
// Also zeroes the ws accumulators + completion counter.
__global__ void rsl_pack_cls(const float* __restrict__ cls,
                             unsigned short* __restrict__ packed,
                             double* __restrict__ ws_sum,
                             unsigned long long* __restrict__ ws_cnt,
                             unsigned int* __restrict__ ws_done)
{
    int t = blockIdx.x * 256 + threadIdx.x;      // 0 .. 16*10*64-1
    if (t == 0) { ws_sum[0] = 0.0; ws_cnt[0] = 0ull; ws_done[0] = 0u; }
    if (t >= 16 * NT_TILES * 64) return;
    int s  = t / (NT_TILES * 64);
    int r  = t - s * (NT_TILES * 64);
    int nt = r >> 6;
    int l  = r & 63;
    int c  = nt * 16 + (l & 15);
    int k  = s * 32 + (l >> 4) * 8;
    unsigned short v[8];
#pragma unroll
    for (int j = 0; j < 8; ++j)
        v[j] = (c < NUM_CLS) ? (unsigned short)f2bf(cls[c * D_DIM + k + j]) : (unsigned short)0;
    u32x4 w;
#pragma unroll
    for (int q = 0; q < 4; ++q)
        w[q] = (unsigned int)v[2 * q] | ((unsigned int)v[2 * q + 1] << 16);
    *(u32x4*)(packed + (size_t)(s * NT_TILES + nt) * 512 + (size_t)l * 8) = w;
}

__global__ __launch_bounds__(256, 3)
void rsl_mfma(const float* __restrict__ pred,
              const unsigned short* __restrict__ packed,
              const int*   __restrict__ idx,
              const int*   __restrict__ lut,
              double* __restrict__ ws_sum,
              unsigned long long* __restrict__ ws_cnt,
              unsigned int* __restrict__ ws_done,
              float* __restrict__ out)
{
    // LDS: pred tile [32 dims][128 px] fp32 (16KB) x2, SWIZZLED layout
    // ([d][p ^ ((d>>3)<<3)]); cls tile 10KB x2. Total 52KB -> 3 blocks/CU.
    __shared__ float          sP[2][32][128];
    __shared__ unsigned short sC[2][NT_TILES][512];

    const int lane = threadIdx.x & 63;
    const int wid  = threadIdx.x >> 6;
    const int row  = lane & 15;      // M-idx in tile (A frag) / N-idx (C/D)
    const int g    = lane >> 4;      // k-group (A frag) / row-group (C/D)

    const int pixbase = blockIdx.x * 128;            // never straddles b (65536%128==0)
    const int b  = pixbase >> 16;
    const int p0 = pixbase & 0xFFFF;
    const float* predb = pred + (size_t)b * D_DIM * HW_DIM;
    const int pxl = (lane & 31) * 4;                 // float offset in tile row
    const int dl  = lane >> 5;                       // which of the 2 dims per DMA op

    f32x4 acc[2][NT_TILES] = {};

// stage pred K-tile ss -> buffer q; instruction t covers dims {2t+dl},
// global pixel offset pre-swizzled by (t>>2)<<3 so linear LDS dest = swizzled layout
#define STAGEP(ss, q) do { \
    const float* srcb_ = predb + (size_t)((ss) * 32) * HW_DIM; \
    _Pragma("unroll") \
    for (int tt = 0; tt < 4; ++tt) { \
        const int t_ = wid * 4 + tt; \
        GLOAD16(srcb_ + (size_t)(2 * t_ + dl) * HW_DIM + (p0 + (pxl ^ ((t_ >> 2) << 3))), \
                &sP[q][2 * t_][0]); \
    } } while (0)

    // ---- prologue: stage s=0 ----
    STAGEP(0, 0);
    for (int nt = wid; nt < NT_TILES; nt += 4)
        GLOAD16(packed + (size_t)nt * 512 + (size_t)lane * 8, &sC[0][nt][0]);
    __syncthreads();

    for (int s = 0; s < 16; ++s) {
        const int cur = s & 1;
        // ---- stage s+1 into the other buffer (async) ----
        if (s < 15) {
            STAGEP(s + 1, cur ^ 1);
            const unsigned short* csrc = packed + (size_t)((s + 1) * NT_TILES) * 512 + (size_t)lane * 8;
            for (int nt = wid; nt < NT_TILES; nt += 4)
                GLOAD16(csrc + (size_t)nt * 512, &sC[cur ^ 1][nt][0]);
        }

        // ---- compute on current buffer (swizzled read: 2-way conflict = free) ----
        bf16x8 pf[2];
#pragma unroll
        for (int mt = 0; mt < 2; ++mt)
#pragma unroll
            for (int j = 0; j < 8; ++j)
                pf[mt][j] = f2bf(sP[cur][g * 8 + j][(wid * 32 + mt * 16 + row) ^ (g << 3)]);

#pragma unroll
        for (int nt = 0; nt < NT_TILES; ++nt) {
            bf16x8 cf = *(const bf16x8*)&sC[cur][nt][lane * 8];
#pragma unroll
            for (int mt = 0; mt < 2; ++mt)
                acc[mt][nt] = __builtin_amdgcn_mfma_f32_16x16x32_bf16(pf[mt], cf, acc[mt][nt], 0, 0, 0);
        }
        __syncthreads();   // drain + barrier: next tile ready, buffers safe
    }

    // ---- epilogue. C/D: class = nt*16 + row, pixel = wid*32 + mt*16 + g*4 + j ----
    const float invT = 1.0f / 0.07f;
    float local_sum = 0.f;
    int   local_cnt = 0;
#pragma unroll
    for (int mt = 0; mt < 2; ++mt) {
#pragma unroll
        for (int j = 0; j < 4; ++j) {
            const int pixg = pixbase + wid * 32 + mt * 16 + g * 4 + j;
            const int lab  = lut[idx[pixg]];
            const bool valid = (lab != IGNORE_L);

            float m = -1e30f;
#pragma unroll
            for (int nt = 0; nt < NT_TILES; ++nt) {
                int c = nt * 16 + row;
                float v = (c < NUM_CLS) ? acc[mt][nt][j] : -1e30f;
                m = fmaxf(m, v);
            }
#pragma unroll
            for (int o = 8; o >= 1; o >>= 1) m = fmaxf(m, __shfl_xor(m, o));

            float ssum = 0.f, slab = 0.f;
#pragma unroll
            for (int nt = 0; nt < NT_TILES; ++nt) {
                int c = nt * 16 + row;
                if (c < NUM_CLS) {
                    float v = acc[mt][nt][j];
                    ssum += __expf((v - m) * invT);
                    slab += (c == lab) ? v : 0.f;
                }
            }
#pragma unroll
            for (int o = 8; o >= 1; o >>= 1) {
                ssum += __shfl_xor(ssum, o);
                slab += __shfl_xor(slab, o);
            }
            if (row == 0 && valid) {
                local_sum += (m - slab) * invT + __logf(ssum);
                local_cnt += 1;
            }
        }
    }

    // wave(64) reduce -> block -> global atomics; last block finalizes out
#pragma unroll
    for (int o = 32; o >= 1; o >>= 1) {
        local_sum += __shfl_down(local_sum, o);
        local_cnt += __shfl_down(local_cnt, o);
    }
    __shared__ float sv[4];
    __shared__ int   sc[4];
    if (lane == 0) { sv[wid] = local_sum; sc[wid] = local_cnt; }
    __syncthreads();
    if (threadIdx.x == 0) {
        float tv = sv[0] + sv[1] + sv[2] + sv[3];
        int   tc = sc[0] + sc[1] + sc[2] + sc[3];
        atomicAdd(ws_sum, (double)tv);
        atomicAdd(ws_cnt, (unsigned long long)tc);
        __threadfence();                              // partials visible before done++
        unsigned int done = atomicAdd(ws_done, 1u);
        if (done == gridDim.x - 1) {                  // last block: all partials in
            double s = atomicAdd(ws_sum, 0.0);        // device-coherent readback
            unsigned long long c = atomicAdd(ws_cnt, 0ull);
            out[0] = (float)(s / (c > 0 ? (double)c : 1.0));
        }
    }
}

extern "C" void kernel_launch(void* const* d_in, const int* in_sizes, int n_in,
                              void* d_out, int out_size, void* d_ws, size_t ws_size,
                              hipStream_t stream)
{
    const float* pred = (const float*)d_in[0];   // (4, 512, 256, 256) fp32
    const float* cls  = (const float*)d_in[1];   // (150, 512) fp32
    const int*   idx  = (const int*)d_in[2];     // (4, 1, 256, 256) int32
    const int*   lut  = (const int*)d_in[3];     // (512,) int32
    float* out = (float*)d_out;

    double* wsd = (double*)d_ws;
    unsigned long long* wsc = (unsigned long long*)((char*)d_ws + 8);
    unsigned int* wsdone = (unsigned int*)((char*)d_ws + 16);
    unsigned short* packed = (unsigned short*)((char*)d_ws + 1024);  // 160 KB

    rsl_pack_cls<<<40, 256, 0, stream>>>(cls, packed, wsd, wsc, wsdone);

    const int total = 4 * HW_DIM;                 // 262144 pixels
    rsl_mfma<<<total / 128, 256, 0, stream>>>(pred, packed, idx, lut, wsd, wsc, wsdone, out);
}

// Round 16
// 129.746 us; speedup vs baseline: 1.5038x; 1.5038x over previous
//
#include <hip/hip_runtime.h>
#include <hip/hip_bf16.h>

// RelativeSemanticLoss via bf16 MFMA GEMM + fused softmax-NLL epilogue.
// R16 = exact revert to R14/R11 (verified best: 129.5-130.0 us).
// 16x16x32 MFMA, async global_load_lds double-buffer, 3 blk/CU, pred LDS
// XOR-swizzle [d][p ^ ((d>>3)<<3)] via pre-swizzled global source (rule #21).
// LESSON (R13/R15): no device-scope fences mid-kernel — __threadfence()
// invalidates the XCD-local L2 (non-coherent L2s), evicting the shared cls
// buffer for co-resident blocks (-65 us).

#define NUM_CLS 150
#define NT_TILES 10      // 160 padded classes
#define D_DIM   512
#define HW_DIM  65536
#define IGNORE_L 255

typedef __attribute__((ext_vector_type(8))) short bf16x8;
typedef __attribute__((ext_vector_type(4))) float f32x4;
typedef __attribute__((ext_vector_type(4))) unsigned int u32x4;

#define GLOAD16(gsrc, ldst) \
    __builtin_amdgcn_global_load_lds((const __attribute__((address_space(1))) void*)(gsrc), \
                                     (__attribute__((address_space(3))) void*)(ldst), 16, 0, 0)

static __device__ __forceinline__ short f2bf(float f) {
    __hip_bfloat16 h = __float2bfloat16(f);   // RNE
    return __builtin_bit_cast(short, h);
}

// Pack cls (150x512 fp32) -> bf16 fragments in lane-linear order:
// packed[(s*10+nt)*512 + l*8 + j] (ushort) = bf16(cls[nt*16+(l&15)][s*32+(l>>4)*8+j])
// Also zeroes the ws accumulators.
__global__ void rsl_pack_cls(const float* __restrict__ cls,
                             unsigned short* __restrict__ packed,
                             double* __restrict__ ws_sum,
                             unsigned long long* __restrict__ ws_cnt)
{
    int t = blockIdx.x * 256 + threadIdx.x;      // 0 .. 16*10*64-1
    if (t == 0) { ws_sum[0] = 0.0; ws_cnt[0] = 0ull; }
    if (t >= 16 * NT_TILES * 64) return;
    int s  = t / (NT_TILES * 64);
    int r  = t - s * (NT_TILES * 64);
    int nt = r >> 6;
    int l  = r & 63;
    int c  = nt * 16 + (l & 15);
    int k  = s * 32 + (l >> 4) * 8;
    unsigned short v[8];
#pragma unroll
    for (int j = 0; j < 8; ++j)
        v[j] = (c < NUM_CLS) ? (unsigned short)f2bf(cls[c * D_DIM + k + j]) : (unsigned short)0;
    u32x4 w;
#pragma unroll
    for (int q = 0; q < 4; ++q)
        w[q] = (unsigned int)v[2 * q] | ((unsigned int)v[2 * q + 1] << 16);
    *(u32x4*)(packed + (size_t)(s * NT_TILES + nt) * 512 + (size_t)l * 8) = w;
}

__global__ __launch_bounds__(256, 3)
void rsl_mfma(const float* __restrict__ pred,
              const unsigned short* __restrict__ packed,
              const int*   __restrict__ idx,
              const int*   __restrict__ lut,
              double* __restrict__ ws_sum,
              unsigned long long* __restrict__ ws_cnt)
{
    // LDS: pred tile [32 dims][128 px] fp32 (16KB) x2, SWIZZLED layout
    // ([d][p ^ ((d>>3)<<3)]); cls tile 10KB x2. Total 52KB -> 3 blocks/CU.
    __shared__ float          sP[2][32][128];
    __shared__ unsigned short sC[2][NT_TILES][512];

    const int lane = threadIdx.x & 63;
    const int wid  = threadIdx.x >> 6;
    const int row  = lane & 15;      // M-idx in tile (A frag) / N-idx (C/D)
    const int g    = lane >> 4;      // k-group (A frag) / row-group (C/D)

    const int pixbase = blockIdx.x * 128;            // never straddles b (65536%128==0)
    const int b  = pixbase >> 16;
    const int p0 = pixbase & 0xFFFF;
    const float* predb = pred + (size_t)b * D_DIM * HW_DIM;
    const int pxl = (lane & 31) * 4;                 // float offset in tile row
    const int dl  = lane >> 5;                       // which of the 2 dims per DMA op

    f32x4 acc[2][NT_TILES] = {};

// stage pred K-tile ss -> buffer q; instruction t covers dims {2t+dl},
// global pixel offset pre-swizzled by (t>>2)<<3 so linear LDS dest = swizzled layout
#define STAGEP(ss, q) do { \
    const float* srcb_ = predb + (size_t)((ss) * 32) * HW_DIM; \
    _Pragma("unroll") \
    for (int tt = 0; tt < 4; ++tt) { \
        const int t_ = wid * 4 + tt; \
        GLOAD16(srcb_ + (size_t)(2 * t_ + dl) * HW_DIM + (p0 + (pxl ^ ((t_ >> 2) << 3))), \
                &sP[q][2 * t_][0]); \
    } } while (0)

    // ---- prologue: stage s=0 ----
    STAGEP(0, 0);
    for (int nt = wid; nt < NT_TILES; nt += 4)
        GLOAD16(packed + (size_t)nt * 512 + (size_t)lane * 8, &sC[0][nt][0]);
    __syncthreads();

    for (int s = 0; s < 16; ++s) {
        const int cur = s & 1;
        // ---- stage s+1 into the other buffer (async) ----
        if (s < 15) {
            STAGEP(s + 1, cur ^ 1);
            const unsigned short* csrc = packed + (size_t)((s + 1) * NT_TILES) * 512 + (size_t)lane * 8;
            for (int nt = wid; nt < NT_TILES; nt += 4)
                GLOAD16(csrc + (size_t)nt * 512, &sC[cur ^ 1][nt][0]);
        }

        // ---- compute on current buffer (swizzled read: 2-way conflict = free) ----
        bf16x8 pf[2];
#pragma unroll
        for (int mt = 0; mt < 2; ++mt)
#pragma unroll
            for (int j = 0; j < 8; ++j)
                pf[mt][j] = f2bf(sP[cur][g * 8 + j][(wid * 32 + mt * 16 + row) ^ (g << 3)]);

#pragma unroll
        for (int nt = 0; nt < NT_TILES; ++nt) {
            bf16x8 cf = *(const bf16x8*)&sC[cur][nt][lane * 8];
#pragma unroll
            for (int mt = 0; mt < 2; ++mt)
                acc[mt][nt] = __builtin_amdgcn_mfma_f32_16x16x32_bf16(pf[mt], cf, acc[mt][nt], 0, 0, 0);
        }
        __syncthreads();   // drain + barrier: next tile ready, buffers safe
    }

    // ---- epilogue. C/D: class = nt*16 + row, pixel = wid*32 + mt*16 + g*4 + j ----
    const float invT = 1.0f / 0.07f;
    float local_sum = 0.f;
    int   local_cnt = 0;
#pragma unroll
    for (int mt = 0; mt < 2; ++mt) {
#pragma unroll
        for (int j = 0; j < 4; ++j) {
            const int pixg = pixbase + wid * 32 + mt * 16 + g * 4 + j;
            const int lab  = lut[idx[pixg]];
            const bool valid = (lab != IGNORE_L);

            float m = -1e30f;
#pragma unroll
            for (int nt = 0; nt < NT_TILES; ++nt) {
                int c = nt * 16 + row;
                float v = (c < NUM_CLS) ? acc[mt][nt][j] : -1e30f;
                m = fmaxf(m, v);
            }
#pragma unroll
            for (int o = 8; o >= 1; o >>= 1) m = fmaxf(m, __shfl_xor(m, o));

            float ssum = 0.f, slab = 0.f;
#pragma unroll
            for (int nt = 0; nt < NT_TILES; ++nt) {
                int c = nt * 16 + row;
                if (c < NUM_CLS) {
                    float v = acc[mt][nt][j];
                    ssum += __expf((v - m) * invT);
                    slab += (c == lab) ? v : 0.f;
                }
            }
#pragma unroll
            for (int o = 8; o >= 1; o >>= 1) {
                ssum += __shfl_xor(ssum, o);
                slab += __shfl_xor(slab, o);
            }
            if (row == 0 && valid) {
                local_sum += (m - slab) * invT + __logf(ssum);
                local_cnt += 1;
            }
        }
    }

    // wave(64) reduce -> block -> global atomics
#pragma unroll
    for (int o = 32; o >= 1; o >>= 1) {
        local_sum += __shfl_down(local_sum, o);
        local_cnt += __shfl_down(local_cnt, o);
    }
    __shared__ float sv[4];
    __shared__ int   sc[4];
    if (lane == 0) { sv[wid] = local_sum; sc[wid] = local_cnt; }
    __syncthreads();
    if (threadIdx.x == 0) {
        float tv = sv[0] + sv[1] + sv[2] + sv[3];
        int   tc = sc[0] + sc[1] + sc[2] + sc[3];
        atomicAdd(ws_sum, (double)tv);
        atomicAdd(ws_cnt, (unsigned long long)tc);
    }
}

__global__ void rsl_final(const double* __restrict__ ws_sum,
                          const unsigned long long* __restrict__ ws_cnt,
                          float* __restrict__ out)
{
    if (threadIdx.x == 0) {
        double c = (double)ws_cnt[0];
        out[0] = (float)(ws_sum[0] / (c > 0.0 ? c : 1.0));
    }
}

extern "C" void kernel_launch(void* const* d_in, const int* in_sizes, int n_in,
                              void* d_out, int out_size, void* d_ws, size_t ws_size,
                              hipStream_t stream)
{
    const float* pred = (const float*)d_in[0];   // (4, 512, 256, 256) fp32
    const float* cls  = (const float*)d_in[1];   // (150, 512) fp32
    const int*   idx  = (const int*)d_in[2];     // (4, 1, 256, 256) int32
    const int*   lut  = (const int*)d_in[3];     // (512,) int32
    float* out = (float*)d_out;

    double* wsd = (double*)d_ws;
    unsigned long long* wsc = (unsigned long long*)((char*)d_ws + 8);
    unsigned short* packed = (unsigned short*)((char*)d_ws + 1024);  // 160 KB

    rsl_pack_cls<<<40, 256, 0, stream>>>(cls, packed, wsd, wsc);

    const int total = 4 * HW_DIM;                 // 262144 pixels
    rsl_mfma<<<total / 128, 256, 0, stream>>>(pred, packed, idx, lut, wsd, wsc);
    rsl_final<<<1, 64, 0, stream>>>(wsd, wsc, out);
}